// Round 2
// baseline (375.339 us; speedup 1.0000x reference)
//
#include <hip/hip_runtime.h>

#define N_NODES 100000
#define N_EDGES 2000000

typedef __bf16 bf16x8 __attribute__((ext_vector_type(8)));
typedef float f32x4 __attribute__((ext_vector_type(4)));

__device__ __forceinline__ unsigned f2bf_rne(float f) {
  unsigned u = __builtin_bit_cast(unsigned, f);
  u += 0x7FFFu + ((u >> 16) & 1u);
  return u >> 16;
}

// Pack two non-negative f32 into bf16x2 with round-half-up (add 0x8000 then
// truncate via v_perm_b32). 3 VALU ops for 2 elements.
__device__ __forceinline__ unsigned pack_rhu(float lo, float hi) {
  unsigned ulo = __builtin_bit_cast(unsigned, lo) + 0x8000u;
  unsigned uhi = __builtin_bit_cast(unsigned, hi) + 0x8000u;
  // bytes 0-1 <- src1(ulo) bytes 2-3 ; bytes 2-3 <- src0(uhi) bytes 2-3
  return __builtin_amdgcn_perm(uhi, ulo, 0x07060302u);
}

// |a-b| for a packed bf16 pair, result packed bf16 pair (~11 VALU).
__device__ __forceinline__ unsigned absdiff_pack(unsigned a, unsigned b) {
  float alo = __builtin_bit_cast(float, a << 16);
  float ahi = __builtin_bit_cast(float, a & 0xFFFF0000u);
  float blo = __builtin_bit_cast(float, b << 16);
  float bhi = __builtin_bit_cast(float, b & 0xFFFF0000u);
  return pack_rhu(fabsf(alo - blo), fabsf(ahi - bhi));
}

// ---------------------------------------------------------------------------
// Node MLP: H = relu(relu(X@W1+b1)@W2+b2) stored bf16 row-major (N x 64).
// One thread per node. h1[k] is computed on the fly inside the k-loop (no
// 64-reg h1 array); the j-dimension lives in acc[64] registers so the W2
// access per k-iteration is one CONSECUTIVE row -> merges into
// s_load_dwordx16 (the previous version issued 64 stride-256B scalar loads
// per iteration and was latency-bound at ~110us).
// ---------------------------------------------------------------------------
__global__ __launch_bounds__(256) void node_mlp_kernel(
    const float* __restrict__ X, const float* __restrict__ W1,
    const float* __restrict__ b1, const float* __restrict__ W2,
    const float* __restrict__ b2, unsigned short* __restrict__ H) {
  int n = blockIdx.x * 256 + threadIdx.x;
  if (n >= N_NODES) return;
  float4 xv = ((const float4*)X)[n];
  float acc[64];
#pragma unroll
  for (int j = 0; j < 64; ++j) acc[j] = b2[j];
#pragma unroll 2
  for (int k = 0; k < 64; ++k) {
    float hk = fmaxf(b1[k] + xv.x * W1[k] + xv.y * W1[64 + k] +
                         xv.z * W1[128 + k] + xv.w * W1[192 + k],
                     0.f);
#pragma unroll
    for (int j = 0; j < 64; ++j) acc[j] = fmaf(hk, W2[k * 64 + j], acc[j]);
  }
  uint4* Hp = (uint4*)(H + n * 64);
#pragma unroll
  for (int q = 0; q < 8; ++q) {
    uint4 o;
    o.x = pack_rhu(fmaxf(acc[q * 8 + 0], 0.f), fmaxf(acc[q * 8 + 1], 0.f));
    o.y = pack_rhu(fmaxf(acc[q * 8 + 2], 0.f), fmaxf(acc[q * 8 + 3], 0.f));
    o.z = pack_rhu(fmaxf(acc[q * 8 + 4], 0.f), fmaxf(acc[q * 8 + 5], 0.f));
    o.w = pack_rhu(fmaxf(acc[q * 8 + 6], 0.f), fmaxf(acc[q * 8 + 7], 0.f));
    Hp[q] = o;
  }
}

// ---------------------------------------------------------------------------
// Edge MLP, operand-swapped MFMA: D[hidden][edge] = We1^T (A) x E^T (B).
//   A-frag (We1^T): lane holds A[m=l15][k=quad*8+j]  -> staged in LDS, read
//     per tile via ds_read_b128 (keeps VGPR ~100 -> 4 waves/SIMD; previous
//     version held 96 regs of weights -> 2 waves/SIMD, 43% idle).
//   B-frag (edges): lane holds B[k=quad*8+j][n=l15]  -> the gathered H rows,
//     identical 16B segments as before.
//   C/D: lane holds rows quad*4+r (hidden), col l15 (edge) -> layer-2 sum is
//     across quads only: 2 shfl_xor, contiguous 16-float stores.
// ---------------------------------------------------------------------------
__global__ __launch_bounds__(256, 4) void edge_mlp_kernel(
    const unsigned short* __restrict__ H, const int* __restrict__ pairs,
    const float* __restrict__ We1, const float* __restrict__ be1,
    const float* __restrict__ We2, const float* __restrict__ be2,
    float* __restrict__ out) {
  __shared__ uint4 wlds[1536];  // 24 frags x 64 lanes x 16B = 24 KB
  const int tid = threadIdx.x;

  // Stage We1 into LDS in A-fragment order: frag f = c*4+mt holds
  // We1[k=32c+quad*8+j][col=mt*16+l15], j=0..7 packed bf16 (RNE).
  for (int s = tid; s < 1536; s += 256) {
    int f = s >> 6;
    int ln = s & 63;
    int c = f >> 2, mt = f & 3;
    int kb = c * 32 + (ln >> 4) * 8;
    int col = mt * 16 + (ln & 15);
    unsigned w[4];
#pragma unroll
    for (int p = 0; p < 4; ++p) {
      unsigned lo = f2bf_rne(We1[(kb + 2 * p) * 64 + col]);
      unsigned hi = f2bf_rne(We1[(kb + 2 * p + 1) * 64 + col]);
      w[p] = lo | (hi << 16);
    }
    wlds[s] = make_uint4(w[0], w[1], w[2], w[3]);
  }

  const int lane = tid & 63;
  const int l15 = lane & 15;
  const int quad = lane >> 4;

  // Per-lane epilogue constants: hidden unit u = mt*16 + quad*4 + r.
  float be1v[16], we2v[16];
#pragma unroll
  for (int mt = 0; mt < 4; ++mt)
#pragma unroll
    for (int r = 0; r < 4; ++r) {
      be1v[mt * 4 + r] = be1[mt * 16 + quad * 4 + r];
      we2v[mt * 4 + r] = We2[mt * 16 + quad * 4 + r];
    }
  const float be2v = be2[0];
  __syncthreads();

  const int wid = blockIdx.x * 4 + (tid >> 6);
  const int nw = gridDim.x * 4;
  const uint4* wfrag = wlds + lane;  // frag f at wfrag[f*64]
  const int ntiles = N_EDGES / 16;

  for (int tile = wid; tile < ntiles; tile += nw) {
    int e = tile * 16 + l15;
    int2 uv = ((const int2*)pairs)[e];
    const uint4* pu = (const uint4*)(H + uv.x * 64 + quad * 8);
    const uint4* pv = (const uint4*)(H + uv.y * 64 + quad * 8);
    uint4 hu0 = pu[0], hu1 = pu[4];  // k [0,32), [32,64) of hu
    uint4 hv0 = pv[0], hv1 = pv[4];
    uint4 ab0, ab1;
    ab0.x = absdiff_pack(hu0.x, hv0.x);
    ab0.y = absdiff_pack(hu0.y, hv0.y);
    ab0.z = absdiff_pack(hu0.z, hv0.z);
    ab0.w = absdiff_pack(hu0.w, hv0.w);
    ab1.x = absdiff_pack(hu1.x, hv1.x);
    ab1.y = absdiff_pack(hu1.y, hv1.y);
    ab1.z = absdiff_pack(hu1.z, hv1.z);
    ab1.w = absdiff_pack(hu1.w, hv1.w);

    bf16x8 b[6];
    b[0] = __builtin_bit_cast(bf16x8, hu0);
    b[1] = __builtin_bit_cast(bf16x8, hu1);
    b[2] = __builtin_bit_cast(bf16x8, hv0);
    b[3] = __builtin_bit_cast(bf16x8, hv1);
    b[4] = __builtin_bit_cast(bf16x8, ab0);
    b[5] = __builtin_bit_cast(bf16x8, ab1);

    f32x4 acc[4];
#pragma unroll
    for (int mt = 0; mt < 4; ++mt) acc[mt] = (f32x4){0.f, 0.f, 0.f, 0.f};
#pragma unroll
    for (int c = 0; c < 6; ++c) {
#pragma unroll
      for (int mt = 0; mt < 4; ++mt) {
        bf16x8 a = __builtin_bit_cast(bf16x8, wfrag[(c * 4 + mt) * 64]);
        acc[mt] =
            __builtin_amdgcn_mfma_f32_16x16x32_bf16(a, b[c], acc[mt], 0, 0, 0);
      }
    }

    float s = 0.f;
#pragma unroll
    for (int mt = 0; mt < 4; ++mt)
#pragma unroll
      for (int r = 0; r < 4; ++r)
        s += fmaxf(acc[mt][r] + be1v[mt * 4 + r], 0.f) * we2v[mt * 4 + r];
    s += __shfl_xor(s, 16);
    s += __shfl_xor(s, 32);
    if (quad == 0) out[tile * 16 + l15] = s + be2v;
  }
}

extern "C" void kernel_launch(void* const* d_in, const int* in_sizes, int n_in,
                              void* d_out, int out_size, void* d_ws,
                              size_t ws_size, hipStream_t stream) {
  const float* X = (const float*)d_in[0];
  const int* pairs = (const int*)d_in[1];
  const float* W1 = (const float*)d_in[2];
  const float* b1 = (const float*)d_in[3];
  const float* W2 = (const float*)d_in[4];
  const float* b2 = (const float*)d_in[5];
  const float* We1 = (const float*)d_in[6];
  const float* be1 = (const float*)d_in[7];
  const float* We2 = (const float*)d_in[8];
  const float* be2 = (const float*)d_in[9];
  float* out = (float*)d_out;
  unsigned short* H = (unsigned short*)d_ws;  // 100000*64 bf16 = 12.8 MB

  node_mlp_kernel<<<(N_NODES + 255) / 256, 256, 0, stream>>>(X, W1, b1, W2, b2,
                                                             H);
  edge_mlp_kernel<<<1024, 256, 0, stream>>>(H, pairs, We1, be1, We2, be2, out);
}

// Round 3
// 183.199 us; speedup vs baseline: 2.0488x; 2.0488x over previous
//
#include <hip/hip_runtime.h>

#define N_NODES 100000
#define N_EDGES 2000000

typedef __bf16 bf16x8 __attribute__((ext_vector_type(8)));
typedef float f32x4 __attribute__((ext_vector_type(4)));

__device__ __forceinline__ unsigned f2bf_rne(float f) {
  unsigned u = __builtin_bit_cast(unsigned, f);
  u += 0x7FFFu + ((u >> 16) & 1u);
  return u >> 16;
}

// Pack two NON-NEGATIVE f32 into bf16x2, round-half-up (3 VALU for 2 elems).
__device__ __forceinline__ unsigned pack_rhu(float lo, float hi) {
  unsigned ulo = __builtin_bit_cast(unsigned, lo) + 0x8000u;
  unsigned uhi = __builtin_bit_cast(unsigned, hi) + 0x8000u;
  return __builtin_amdgcn_perm(uhi, ulo, 0x07060302u);
}

// |a-b| on a packed bf16 pair -> packed bf16 pair (~7 VALU, no us8 scalarize).
__device__ __forceinline__ unsigned absdiff_pack(unsigned a, unsigned b) {
  float alo = __builtin_bit_cast(float, a << 16);
  float ahi = __builtin_bit_cast(float, a & 0xFFFF0000u);
  float blo = __builtin_bit_cast(float, b << 16);
  float bhi = __builtin_bit_cast(float, b & 0xFFFF0000u);
  return pack_rhu(fabsf(alo - blo), fabsf(ahi - bhi));
}

// ---------------------------------------------------------------------------
// Fused node MLP via MFMA. One wave per 16-node tile (6250 blocks x 64 thr).
// Lane computes h1[k] for node l15 directly in MFMA B-frag layout
// (B[k=c*32+quad*8+j][n=l15]); W1 columns + W2^T A-frags live in registers
// (loaded once, ~115 regs). No H1 materialization, no scalar-load latency
// chain (round-1/2's node kernel was ~100us, serialized on uniform s_loads).
// D[row=out_hid][col=node]; epilogue packs 4 bf16 per mt into one dwordx2.
// ---------------------------------------------------------------------------
__global__ __launch_bounds__(64) void node_mfma_kernel(
    const float* __restrict__ X, const float* __restrict__ W1,
    const float* __restrict__ b1, const float* __restrict__ W2,
    const float* __restrict__ b2, unsigned short* __restrict__ H) {
  const int lane = threadIdx.x;
  const int l15 = lane & 15;
  const int quad = lane >> 4;

  // W1 columns this lane needs: cols c*32+quad*8+j, c=0..1, j=0..7, d=0..3.
  float w1v[2][4][8], b1v[2][8];
#pragma unroll
  for (int c = 0; c < 2; ++c)
#pragma unroll
    for (int j = 0; j < 8; ++j) {
      int col = c * 32 + quad * 8 + j;
      b1v[c][j] = b1[col];
#pragma unroll
      for (int d = 0; d < 4; ++d) w1v[c][d][j] = W1[d * 64 + col];
    }

  // W2^T A-frags: afr[c][mt] elem j = W2[(c*32+quad*8+j)*64 + mt*16+l15].
  uint4 afr[2][4];
#pragma unroll
  for (int c = 0; c < 2; ++c)
#pragma unroll
    for (int mt = 0; mt < 4; ++mt) {
      unsigned w[4];
#pragma unroll
      for (int p = 0; p < 4; ++p) {
        int k = c * 32 + quad * 8 + 2 * p;
        unsigned lo = f2bf_rne(W2[k * 64 + mt * 16 + l15]);
        unsigned hi = f2bf_rne(W2[(k + 1) * 64 + mt * 16 + l15]);
        w[p] = lo | (hi << 16);
      }
      afr[c][mt] = make_uint4(w[0], w[1], w[2], w[3]);
    }
  float b2v[16];
#pragma unroll
  for (int mt = 0; mt < 4; ++mt)
#pragma unroll
    for (int r = 0; r < 4; ++r) b2v[mt * 4 + r] = b2[mt * 16 + quad * 4 + r];

  const int tile = blockIdx.x;  // exactly N_NODES/16 blocks
  float4 xv = ((const float4*)X)[tile * 16 + l15];

  // h1 in B-frag layout, bf16-packed.
  uint4 bfr[2];
#pragma unroll
  for (int c = 0; c < 2; ++c) {
    unsigned w[4];
#pragma unroll
    for (int p = 0; p < 4; ++p) {
      float h0 = fmaxf(b1v[c][2 * p] + xv.x * w1v[c][0][2 * p] +
                           xv.y * w1v[c][1][2 * p] + xv.z * w1v[c][2][2 * p] +
                           xv.w * w1v[c][3][2 * p],
                       0.f);
      float h1 = fmaxf(b1v[c][2 * p + 1] + xv.x * w1v[c][0][2 * p + 1] +
                           xv.y * w1v[c][1][2 * p + 1] +
                           xv.z * w1v[c][2][2 * p + 1] +
                           xv.w * w1v[c][3][2 * p + 1],
                       0.f);
      w[p] = pack_rhu(h0, h1);
    }
    bfr[c] = make_uint4(w[0], w[1], w[2], w[3]);
  }

  f32x4 acc[4];
#pragma unroll
  for (int mt = 0; mt < 4; ++mt) acc[mt] = (f32x4){0.f, 0.f, 0.f, 0.f};
#pragma unroll
  for (int c = 0; c < 2; ++c)
#pragma unroll
    for (int mt = 0; mt < 4; ++mt)
      acc[mt] = __builtin_amdgcn_mfma_f32_16x16x32_bf16(
          __builtin_bit_cast(bf16x8, afr[c][mt]),
          __builtin_bit_cast(bf16x8, bfr[c]), acc[mt], 0, 0, 0);

  // Store H[node=tile*16+l15][hid=mt*16+quad*4+r] as packed bf16, 8B/lane/mt.
  unsigned short* hrow = H + (tile * 16 + l15) * 64;
#pragma unroll
  for (int mt = 0; mt < 4; ++mt) {
    unsigned lo = pack_rhu(fmaxf(acc[mt][0] + b2v[mt * 4 + 0], 0.f),
                           fmaxf(acc[mt][1] + b2v[mt * 4 + 1], 0.f));
    unsigned hi = pack_rhu(fmaxf(acc[mt][2] + b2v[mt * 4 + 2], 0.f),
                           fmaxf(acc[mt][3] + b2v[mt * 4 + 3], 0.f));
    *(uint2*)(hrow + mt * 16 + quad * 4) = make_uint2(lo, hi);
  }
}

// ---------------------------------------------------------------------------
// Edge MLP. A = We1^T in persistent registers (96 VGPRs, as round-1 which ran
// 128us; round-2's LDS+spill variant thrashed L2 with scratch traffic).
// B = gathered edge features. D[row=hid][col=edge] -> 2-shfl epilogue,
// contiguous stores. 2-deep pipeline: pairs fetched 2 tiles ahead, H-row
// gathers issued 1 tile ahead, hiding ~700-900cyc gather latency at
// 2 waves/SIMD. launch_bounds(256,2) -> 256-VGPR cap, nothing spills.
// ---------------------------------------------------------------------------
__global__ __launch_bounds__(256, 2) void edge_mlp_kernel(
    const unsigned short* __restrict__ H, const int* __restrict__ pairs,
    const float* __restrict__ We1, const float* __restrict__ be1,
    const float* __restrict__ We2, const float* __restrict__ be2,
    float* __restrict__ out) {
  const int tid = threadIdx.x;
  const int lane = tid & 63;
  const int l15 = lane & 15;
  const int quad = lane >> 4;

  // Persistent We1^T A-frags: afr[c][mt] elem j =
  // We1[(c*32+quad*8+j)*64 + mt*16+l15], c=0..5, mt=0..3. 96 VGPRs.
  uint4 afr[6][4];
#pragma unroll
  for (int c = 0; c < 6; ++c)
#pragma unroll
    for (int mt = 0; mt < 4; ++mt) {
      unsigned w[4];
#pragma unroll
      for (int p = 0; p < 4; ++p) {
        int k = c * 32 + quad * 8 + 2 * p;
        unsigned lo = f2bf_rne(We1[k * 64 + mt * 16 + l15]);
        unsigned hi = f2bf_rne(We1[(k + 1) * 64 + mt * 16 + l15]);
        w[p] = lo | (hi << 16);
      }
      afr[c][mt] = make_uint4(w[0], w[1], w[2], w[3]);
    }
  float be1v[16], we2v[16];
#pragma unroll
  for (int mt = 0; mt < 4; ++mt)
#pragma unroll
    for (int r = 0; r < 4; ++r) {
      be1v[mt * 4 + r] = be1[mt * 16 + quad * 4 + r];
      we2v[mt * 4 + r] = We2[mt * 16 + quad * 4 + r];
    }
  const float be2v = be2[0];

  const int wid = blockIdx.x * 4 + (tid >> 6);
  const int nw = gridDim.x * 4;
  const int ntiles = N_EDGES / 16;
  const int2* pairs2 = (const int2*)pairs;

  // Prologue: pairs for t0 and t1, gathers for t0.
  int t1 = wid + nw;
  int2 uvA = pairs2[wid * 16 + l15];
  int2 uvB = pairs2[(t1 < ntiles ? t1 : wid) * 16 + l15];
  const uint4* pu = (const uint4*)(H + uvA.x * 64 + quad * 8);
  const uint4* pv = (const uint4*)(H + uvA.y * 64 + quad * 8);
  uint4 g0 = pu[0], g1 = pu[4], g2 = pv[0], g3 = pv[4];

  for (int tile = wid; tile < ntiles; tile += nw) {
    // Issue next tile's gathers (addresses ready: uvB loaded last iter).
    const uint4* qu = (const uint4*)(H + uvB.x * 64 + quad * 8);
    const uint4* qv = (const uint4*)(H + uvB.y * 64 + quad * 8);
    uint4 n0 = qu[0], n1 = qu[4], n2 = qv[0], n3 = qv[4];
    // Pairs for tile+2.
    int t2 = tile + 2 * nw;
    int2 uvC = pairs2[(t2 < ntiles ? t2 : tile) * 16 + l15];

    // |hu-hv| on packed dwords.
    uint4 ab0, ab1;
    ab0.x = absdiff_pack(g0.x, g2.x);
    ab0.y = absdiff_pack(g0.y, g2.y);
    ab0.z = absdiff_pack(g0.z, g2.z);
    ab0.w = absdiff_pack(g0.w, g2.w);
    ab1.x = absdiff_pack(g1.x, g3.x);
    ab1.y = absdiff_pack(g1.y, g3.y);
    ab1.z = absdiff_pack(g1.z, g3.z);
    ab1.w = absdiff_pack(g1.w, g3.w);

    bf16x8 b[6];
    b[0] = __builtin_bit_cast(bf16x8, g0);
    b[1] = __builtin_bit_cast(bf16x8, g1);
    b[2] = __builtin_bit_cast(bf16x8, g2);
    b[3] = __builtin_bit_cast(bf16x8, g3);
    b[4] = __builtin_bit_cast(bf16x8, ab0);
    b[5] = __builtin_bit_cast(bf16x8, ab1);

    f32x4 acc[4];
#pragma unroll
    for (int mt = 0; mt < 4; ++mt) acc[mt] = (f32x4){0.f, 0.f, 0.f, 0.f};
#pragma unroll
    for (int c = 0; c < 6; ++c)
#pragma unroll
      for (int mt = 0; mt < 4; ++mt)
        acc[mt] = __builtin_amdgcn_mfma_f32_16x16x32_bf16(
            __builtin_bit_cast(bf16x8, afr[c][mt]), b[c], acc[mt], 0, 0, 0);

    float s = 0.f;
#pragma unroll
    for (int mt = 0; mt < 4; ++mt)
#pragma unroll
      for (int r = 0; r < 4; ++r)
        s += fmaxf(acc[mt][r] + be1v[mt * 4 + r], 0.f) * we2v[mt * 4 + r];
    s += __shfl_xor(s, 16);
    s += __shfl_xor(s, 32);
    if (quad == 0) out[tile * 16 + l15] = s + be2v;

    g0 = n0;
    g1 = n1;
    g2 = n2;
    g3 = n3;
    uvB = uvC;
  }
}

extern "C" void kernel_launch(void* const* d_in, const int* in_sizes, int n_in,
                              void* d_out, int out_size, void* d_ws,
                              size_t ws_size, hipStream_t stream) {
  const float* X = (const float*)d_in[0];
  const int* pairs = (const int*)d_in[1];
  const float* W1 = (const float*)d_in[2];
  const float* b1 = (const float*)d_in[3];
  const float* W2 = (const float*)d_in[4];
  const float* b2 = (const float*)d_in[5];
  const float* We1 = (const float*)d_in[6];
  const float* be1 = (const float*)d_in[7];
  const float* We2 = (const float*)d_in[8];
  const float* be2 = (const float*)d_in[9];
  float* out = (float*)d_out;
  unsigned short* H = (unsigned short*)d_ws;  // 100000*64 bf16 = 12.8 MB

  node_mfma_kernel<<<N_NODES / 16, 64, 0, stream>>>(X, W1, b1, W2, b2, H);
  edge_mlp_kernel<<<1024, 256, 0, stream>>>(H, pairs, We1, be1, We2, be2, out);
}

// Round 4
// 182.992 us; speedup vs baseline: 2.0511x; 1.0011x over previous
//
#include <hip/hip_runtime.h>

#define N_NODES 100000
#define N_EDGES 2000000

typedef __bf16 bf16x8 __attribute__((ext_vector_type(8)));
typedef float f32x4 __attribute__((ext_vector_type(4)));

__device__ __forceinline__ unsigned f2bf_rne(float f) {
  unsigned u = __builtin_bit_cast(unsigned, f);
  u += 0x7FFFu + ((u >> 16) & 1u);
  return u >> 16;
}

// Pack two NON-NEGATIVE f32 into bf16x2, round-half-up (3 VALU for 2 elems).
__device__ __forceinline__ unsigned pack_rhu(float lo, float hi) {
  unsigned ulo = __builtin_bit_cast(unsigned, lo) + 0x8000u;
  unsigned uhi = __builtin_bit_cast(unsigned, hi) + 0x8000u;
  return __builtin_amdgcn_perm(uhi, ulo, 0x07060302u);
}

// |a-b| on a packed bf16 pair -> packed bf16 pair (~7 VALU).
__device__ __forceinline__ unsigned absdiff_pack(unsigned a, unsigned b) {
  float alo = __builtin_bit_cast(float, a << 16);
  float ahi = __builtin_bit_cast(float, a & 0xFFFF0000u);
  float blo = __builtin_bit_cast(float, b << 16);
  float bhi = __builtin_bit_cast(float, b & 0xFFFF0000u);
  return pack_rhu(fabsf(alo - blo), fabsf(ahi - bhi));
}

// ---------------------------------------------------------------------------
// Fused node MLP via MFMA, grid-stride. Each wave loads W1 columns + W2^T
// A-frags ONCE, then processes ~6 sixteen-node tiles (round-3 ran one tile
// per wave: 6250 blocks each paying the ~150-load setup for 16 nodes —
// setup:work 10:1, ~80us). launch_bounds(64,1) -> VGPR cap 512, no spill.
// ---------------------------------------------------------------------------
__global__ __launch_bounds__(64, 1) void node_mfma_kernel(
    const float* __restrict__ X, const float* __restrict__ W1,
    const float* __restrict__ b1, const float* __restrict__ W2,
    const float* __restrict__ b2, unsigned short* __restrict__ H) {
  const int lane = threadIdx.x;
  const int l15 = lane & 15;
  const int quad = lane >> 4;

  // W1 columns this lane needs: cols c*32+quad*8+j, c=0..1, j=0..7, d=0..3.
  float w1v[2][4][8], b1v[2][8];
#pragma unroll
  for (int c = 0; c < 2; ++c)
#pragma unroll
    for (int j = 0; j < 8; ++j) {
      int col = c * 32 + quad * 8 + j;
      b1v[c][j] = b1[col];
#pragma unroll
      for (int d = 0; d < 4; ++d) w1v[c][d][j] = W1[d * 64 + col];
    }

  // W2^T A-frags: afr[c][mt] elem j = W2[(c*32+quad*8+j)*64 + mt*16+l15].
  uint4 afr[2][4];
#pragma unroll
  for (int c = 0; c < 2; ++c)
#pragma unroll
    for (int mt = 0; mt < 4; ++mt) {
      unsigned w[4];
#pragma unroll
      for (int p = 0; p < 4; ++p) {
        int k = c * 32 + quad * 8 + 2 * p;
        unsigned lo = f2bf_rne(W2[k * 64 + mt * 16 + l15]);
        unsigned hi = f2bf_rne(W2[(k + 1) * 64 + mt * 16 + l15]);
        w[p] = lo | (hi << 16);
      }
      afr[c][mt] = make_uint4(w[0], w[1], w[2], w[3]);
    }
  float b2v[16];
#pragma unroll
  for (int mt = 0; mt < 4; ++mt)
#pragma unroll
    for (int r = 0; r < 4; ++r) b2v[mt * 4 + r] = b2[mt * 16 + quad * 4 + r];

  const int ntiles = N_NODES / 16;  // 6250
  for (int tile = blockIdx.x; tile < ntiles; tile += gridDim.x) {
    float4 xv = ((const float4*)X)[tile * 16 + l15];

    // h1 in B-frag layout, bf16-packed.
    uint4 bfr[2];
#pragma unroll
    for (int c = 0; c < 2; ++c) {
      unsigned w[4];
#pragma unroll
      for (int p = 0; p < 4; ++p) {
        float h0 = fmaxf(b1v[c][2 * p] + xv.x * w1v[c][0][2 * p] +
                             xv.y * w1v[c][1][2 * p] + xv.z * w1v[c][2][2 * p] +
                             xv.w * w1v[c][3][2 * p],
                         0.f);
        float h1 = fmaxf(b1v[c][2 * p + 1] + xv.x * w1v[c][0][2 * p + 1] +
                             xv.y * w1v[c][1][2 * p + 1] +
                             xv.z * w1v[c][2][2 * p + 1] +
                             xv.w * w1v[c][3][2 * p + 1],
                         0.f);
        w[p] = pack_rhu(h0, h1);
      }
      bfr[c] = make_uint4(w[0], w[1], w[2], w[3]);
    }

    f32x4 acc[4];
#pragma unroll
    for (int mt = 0; mt < 4; ++mt) acc[mt] = (f32x4){0.f, 0.f, 0.f, 0.f};
#pragma unroll
    for (int c = 0; c < 2; ++c)
#pragma unroll
      for (int mt = 0; mt < 4; ++mt)
        acc[mt] = __builtin_amdgcn_mfma_f32_16x16x32_bf16(
            __builtin_bit_cast(bf16x8, afr[c][mt]),
            __builtin_bit_cast(bf16x8, bfr[c]), acc[mt], 0, 0, 0);

    unsigned short* hrow = H + (tile * 16 + l15) * 64;
#pragma unroll
    for (int mt = 0; mt < 4; ++mt) {
      unsigned lo = pack_rhu(fmaxf(acc[mt][0] + b2v[mt * 4 + 0], 0.f),
                             fmaxf(acc[mt][1] + b2v[mt * 4 + 1], 0.f));
      unsigned hi = pack_rhu(fmaxf(acc[mt][2] + b2v[mt * 4 + 2], 0.f),
                             fmaxf(acc[mt][3] + b2v[mt * 4 + 3], 0.f));
      *(uint2*)(hrow + mt * 16 + quad * 4) = make_uint2(lo, hi);
    }
  }
}

// ---------------------------------------------------------------------------
// Edge MLP. A = We1^T persistent in registers (96 regs); B = gathered edge
// features; D[row=hid][col=edge] -> 2-shfl epilogue, contiguous stores.
// 2-DEEP gather pipeline: gathers for tile+2 issued now (~220 regs total,
// under the 256 cap of launch_bounds(256,2) -> no spill), putting ~2x
// compute (~900cyc) between gather issue and use, covering the L3-serve
// latency that left round-3 ~40% stalled.
// ---------------------------------------------------------------------------
__global__ __launch_bounds__(256, 2) void edge_mlp_kernel(
    const unsigned short* __restrict__ H, const int* __restrict__ pairs,
    const float* __restrict__ We1, const float* __restrict__ be1,
    const float* __restrict__ We2, const float* __restrict__ be2,
    float* __restrict__ out) {
  const int tid = threadIdx.x;
  const int lane = tid & 63;
  const int l15 = lane & 15;
  const int quad = lane >> 4;

  uint4 afr[6][4];
#pragma unroll
  for (int c = 0; c < 6; ++c)
#pragma unroll
    for (int mt = 0; mt < 4; ++mt) {
      unsigned w[4];
#pragma unroll
      for (int p = 0; p < 4; ++p) {
        int k = c * 32 + quad * 8 + 2 * p;
        unsigned lo = f2bf_rne(We1[k * 64 + mt * 16 + l15]);
        unsigned hi = f2bf_rne(We1[(k + 1) * 64 + mt * 16 + l15]);
        w[p] = lo | (hi << 16);
      }
      afr[c][mt] = make_uint4(w[0], w[1], w[2], w[3]);
    }
  float be1v[16], we2v[16];
#pragma unroll
  for (int mt = 0; mt < 4; ++mt)
#pragma unroll
    for (int r = 0; r < 4; ++r) {
      be1v[mt * 4 + r] = be1[mt * 16 + quad * 4 + r];
      we2v[mt * 4 + r] = We2[mt * 16 + quad * 4 + r];
    }
  const float be2v = be2[0];

  const int wid = blockIdx.x * 4 + (tid >> 6);
  const int nw = gridDim.x * 4;
  const int ntiles = N_EDGES / 16;
  const int2* pairs2 = (const int2*)pairs;

  // Prologue: pairs for t, t+1, t+2; gathers for t and t+1 in flight.
  int t1 = wid + nw, t2 = wid + 2 * nw;
  int2 uv0 = pairs2[wid * 16 + l15];
  int2 uv1 = pairs2[(t1 < ntiles ? t1 : wid) * 16 + l15];
  int2 uv2 = pairs2[(t2 < ntiles ? t2 : wid) * 16 + l15];
  const uint4* pu = (const uint4*)(H + uv0.x * 64 + quad * 8);
  const uint4* pv = (const uint4*)(H + uv0.y * 64 + quad * 8);
  uint4 g0 = pu[0], g1 = pu[4], g2 = pv[0], g3 = pv[4];
  const uint4* ru = (const uint4*)(H + uv1.x * 64 + quad * 8);
  const uint4* rv = (const uint4*)(H + uv1.y * 64 + quad * 8);
  uint4 h0 = ru[0], h1 = ru[4], h2 = rv[0], h3 = rv[4];

  for (int tile = wid; tile < ntiles; tile += nw) {
    // Issue gathers for tile+2 (addresses from uv2, loaded 2 iters back).
    const uint4* qu = (const uint4*)(H + uv2.x * 64 + quad * 8);
    const uint4* qv = (const uint4*)(H + uv2.y * 64 + quad * 8);
    uint4 i0 = qu[0], i1 = qu[4], i2 = qv[0], i3 = qv[4];
    // Pairs for tile+3.
    int t3 = tile + 3 * nw;
    int2 uvn = pairs2[(t3 < ntiles ? t3 : tile) * 16 + l15];

    // Compute on g* (arrived two iterations of prefetch ago).
    uint4 ab0, ab1;
    ab0.x = absdiff_pack(g0.x, g2.x);
    ab0.y = absdiff_pack(g0.y, g2.y);
    ab0.z = absdiff_pack(g0.z, g2.z);
    ab0.w = absdiff_pack(g0.w, g2.w);
    ab1.x = absdiff_pack(g1.x, g3.x);
    ab1.y = absdiff_pack(g1.y, g3.y);
    ab1.z = absdiff_pack(g1.z, g3.z);
    ab1.w = absdiff_pack(g1.w, g3.w);

    bf16x8 b[6];
    b[0] = __builtin_bit_cast(bf16x8, g0);
    b[1] = __builtin_bit_cast(bf16x8, g1);
    b[2] = __builtin_bit_cast(bf16x8, g2);
    b[3] = __builtin_bit_cast(bf16x8, g3);
    b[4] = __builtin_bit_cast(bf16x8, ab0);
    b[5] = __builtin_bit_cast(bf16x8, ab1);

    f32x4 acc[4];
#pragma unroll
    for (int mt = 0; mt < 4; ++mt) acc[mt] = (f32x4){0.f, 0.f, 0.f, 0.f};
#pragma unroll
    for (int c = 0; c < 6; ++c)
#pragma unroll
      for (int mt = 0; mt < 4; ++mt)
        acc[mt] = __builtin_amdgcn_mfma_f32_16x16x32_bf16(
            __builtin_bit_cast(bf16x8, afr[c][mt]), b[c], acc[mt], 0, 0, 0);

    float s = 0.f;
#pragma unroll
    for (int mt = 0; mt < 4; ++mt)
#pragma unroll
      for (int r = 0; r < 4; ++r)
        s += fmaxf(acc[mt][r] + be1v[mt * 4 + r], 0.f) * we2v[mt * 4 + r];
    s += __shfl_xor(s, 16);
    s += __shfl_xor(s, 32);
    if (quad == 0) out[tile * 16 + l15] = s + be2v;

    // Rotate pipeline.
    g0 = h0; g1 = h1; g2 = h2; g3 = h3;
    h0 = i0; h1 = i1; h2 = i2; h3 = i3;
    uv2 = uvn;
  }
}

extern "C" void kernel_launch(void* const* d_in, const int* in_sizes, int n_in,
                              void* d_out, int out_size, void* d_ws,
                              size_t ws_size, hipStream_t stream) {
  const float* X = (const float*)d_in[0];
  const int* pairs = (const int*)d_in[1];
  const float* W1 = (const float*)d_in[2];
  const float* b1 = (const float*)d_in[3];
  const float* W2 = (const float*)d_in[4];
  const float* b2 = (const float*)d_in[5];
  const float* We1 = (const float*)d_in[6];
  const float* be1 = (const float*)d_in[7];
  const float* We2 = (const float*)d_in[8];
  const float* be2 = (const float*)d_in[9];
  float* out = (float*)d_out;
  unsigned short* H = (unsigned short*)d_ws;  // 100000*64 bf16 = 12.8 MB

  node_mfma_kernel<<<1024, 64, 0, stream>>>(X, W1, b1, W2, b2, H);
  edge_mlp_kernel<<<1024, 256, 0, stream>>>(H, pairs, We1, be1, We2, be2, out);
}